// Round 1
// baseline (793.615 us; speedup 1.0000x reference)
//
#include <hip/hip_runtime.h>

#define IN_CH  256
#define HCC    256   // HEADS*OUT_CH
#define HEADS  4
#define OUTC   64
#define NEG_SLOPE 0.2f

// ---------------------------------------------------------------------------
// Kernel 1: x_lin = X @ W   (fp32, 64x64 tile, K staged 64 at a time)
// A staged transposed in LDS so inner loop is 2x ds_read_b128 + 16 FMA.
// ---------------------------------------------------------------------------
__global__ __launch_bounds__(256) void k_gemm(const float* __restrict__ X,
                                              const float* __restrict__ W,
                                              float* __restrict__ XL, int N) {
    __shared__ float Ats[64][68];  // [k][m], pad 68 -> 16B-aligned rows
    __shared__ float Bs[64][68];   // [k][n]
    const int tid = threadIdx.x;
    const int tx = tid & 15, ty = tid >> 4;
    const int m0 = blockIdx.x * 64;
    const int n0 = blockIdx.y * 64;
    float acc[4][4] = {{0.f, 0.f, 0.f, 0.f}};

    for (int kb = 0; kb < IN_CH; kb += 64) {
#pragma unroll
        for (int it = 0; it < 4; ++it) {
            int v = tid + 256 * it;
            int row = v >> 4;          // 0..63
            int c4 = (v & 15) << 2;    // 0..60
            int gr = m0 + row;
            float4 av = make_float4(0.f, 0.f, 0.f, 0.f);
            if (gr < N) av = *(const float4*)(X + (size_t)gr * IN_CH + kb + c4);
            Ats[c4 + 0][row] = av.x;
            Ats[c4 + 1][row] = av.y;
            Ats[c4 + 2][row] = av.z;
            Ats[c4 + 3][row] = av.w;
            float4 bv = *(const float4*)(W + (size_t)(kb + row) * HCC + n0 + c4);
            *(float4*)&Bs[row][c4] = bv;
        }
        __syncthreads();
#pragma unroll 8
        for (int k = 0; k < 64; ++k) {
            float4 a = *(const float4*)&Ats[k][ty << 2];
            float4 b = *(const float4*)&Bs[k][tx << 2];
            float av4[4] = {a.x, a.y, a.z, a.w};
            float bv4[4] = {b.x, b.y, b.z, b.w};
#pragma unroll
            for (int i = 0; i < 4; ++i)
#pragma unroll
                for (int j = 0; j < 4; ++j)
                    acc[i][j] = fmaf(av4[i], bv4[j], acc[i][j]);
        }
        __syncthreads();
    }
#pragma unroll
    for (int i = 0; i < 4; ++i) {
        int gr = m0 + (ty << 2) + i;
        if (gr < N) {
            float4 o = make_float4(acc[i][0], acc[i][1], acc[i][2], acc[i][3]);
            *(float4*)(XL + (size_t)gr * HCC + n0 + (tx << 2)) = o;
        }
    }
}

// ---------------------------------------------------------------------------
// Kernel 2: per-node attention logits a_src[n,h], a_dst[n,h]
// One wave per node; lane loads float4 of its row; 16-lane group = one head.
// ---------------------------------------------------------------------------
__global__ __launch_bounds__(256) void k_att(const float* __restrict__ XL,
                                             const float* __restrict__ ASRC,
                                             const float* __restrict__ ADST,
                                             float* __restrict__ a_s,
                                             float* __restrict__ a_d, int N) {
    int wid = threadIdx.x >> 6;
    int lane = threadIdx.x & 63;
    int n = blockIdx.x * 4 + wid;
    if (n >= N) return;
    float4 xv = *(const float4*)(XL + (size_t)n * HCC + lane * 4);
    int h = lane >> 4;
    int c4 = (lane & 15) << 2;
    float4 sv = *(const float4*)(ASRC + h * OUTC + c4);
    float4 dv = *(const float4*)(ADST + h * OUTC + c4);
    float ds = xv.x * sv.x + xv.y * sv.y + xv.z * sv.z + xv.w * sv.w;
    float dd = xv.x * dv.x + xv.y * dv.y + xv.z * dv.z + xv.w * dv.w;
#pragma unroll
    for (int o = 1; o < 16; o <<= 1) {
        ds += __shfl_xor(ds, o);
        dd += __shfl_xor(dd, o);
    }
    if ((lane & 15) == 0) {
        a_s[(size_t)n * HEADS + h] = ds;
        a_d[(size_t)n * HEADS + h] = dd;
    }
}

// ---------------------------------------------------------------------------
// CSR build: degree histogram, 2-level scan, scatter (src stored per slot).
// Self-loops appended as indices E..E+N-1.
// ---------------------------------------------------------------------------
__global__ void k_deg(const int* __restrict__ ei, int* __restrict__ deg,
                      int E, int N) {
    int i = blockIdx.x * 256 + threadIdx.x;
    int ET = E + N;
    if (i >= ET) return;
    int dst = (i < E) ? ei[E + i] : (i - E);
    atomicAdd(&deg[dst], 1);
}

__global__ void k_scan1(const int* __restrict__ in, int* __restrict__ part,
                        int* __restrict__ bsum, int N) {
    __shared__ int s[256];
    int t = threadIdx.x;
    int i = blockIdx.x * 256 + t;
    int v = (i < N) ? in[i] : 0;
    s[t] = v;
    __syncthreads();
    for (int off = 1; off < 256; off <<= 1) {
        int x = (t >= off) ? s[t - off] : 0;
        __syncthreads();
        s[t] += x;
        __syncthreads();
    }
    if (i < N) part[i] = s[t];
    if (t == 255) bsum[blockIdx.x] = s[255];
}

__global__ void k_scan2(const int* __restrict__ bsum, int* __restrict__ binc,
                        int nb) {
    __shared__ int s[512];
    int t = threadIdx.x;
    s[t] = (t < nb) ? bsum[t] : 0;
    __syncthreads();
    for (int off = 1; off < 512; off <<= 1) {
        int x = (t >= off) ? s[t - off] : 0;
        __syncthreads();
        s[t] += x;
        __syncthreads();
    }
    binc[t] = s[t];
}

__global__ void k_scan3(const int* __restrict__ part,
                        const int* __restrict__ binc,
                        int* __restrict__ rowptr, int N) {
    int b = blockIdx.x;
    int i = b * 256 + threadIdx.x;
    if (i >= N) return;
    int off = (b > 0) ? binc[b - 1] : 0;
    rowptr[i + 1] = part[i] + off;
    if (i == 0) rowptr[0] = 0;
}

__global__ void k_scatter(const int* __restrict__ ei, int* __restrict__ fill,
                          int* __restrict__ eid, int E, int N) {
    int i = blockIdx.x * 256 + threadIdx.x;
    int ET = E + N;
    if (i >= ET) return;
    int src, dst;
    if (i < E) {
        src = ei[i];
        dst = ei[E + i];
    } else {
        src = dst = i - E;
    }
    int pos = atomicAdd(&fill[dst], 1);
    eid[pos] = src;
}

// ---------------------------------------------------------------------------
// Kernel 3: per-dst online-softmax aggregation.
// One block per node; thread t owns output channel t; wave = head.
// ---------------------------------------------------------------------------
__global__ __launch_bounds__(256) void k_agg(const int* __restrict__ rowptr,
                                             const int* __restrict__ eid,
                                             const float* __restrict__ a_s,
                                             const float* __restrict__ a_d,
                                             const float* __restrict__ XL,
                                             const float* __restrict__ BIAS,
                                             float* __restrict__ OUT) {
    int n = blockIdx.x;
    int t = threadIdx.x;
    int h = t >> 6;
    int s0 = rowptr[n];
    int s1 = rowptr[n + 1];
    float adn = a_d[(size_t)n * HEADS + h];
    float m = -3.0e38f, s = 0.f, acc = 0.f;
    for (int e = s0; e < s1; ++e) {
        int src = eid[e];
        float l = a_s[(size_t)src * HEADS + h] + adn;
        l = (l > 0.f) ? l : NEG_SLOPE * l;
        float mn = fmaxf(m, l);
        float scale = __expf(m - mn);
        float p = __expf(l - mn);
        s = s * scale + p;
        acc = acc * scale + p * XL[(size_t)src * HCC + t];
        m = mn;
    }
    OUT[(size_t)n * HCC + t] = acc / (s + 1e-16f) + BIAS[t];
}

// ---------------------------------------------------------------------------
extern "C" void kernel_launch(void* const* d_in, const int* in_sizes, int n_in,
                              void* d_out, int out_size, void* d_ws,
                              size_t ws_size, hipStream_t stream) {
    const float* X = (const float*)d_in[0];
    const int* EI = (const int*)d_in[1];
    const float* W = (const float*)d_in[2];
    const float* ASRC = (const float*)d_in[3];
    const float* ADST = (const float*)d_in[4];
    const float* BIAS = (const float*)d_in[5];
    float* OUT = (float*)d_out;

    const int N = in_sizes[0] / IN_CH;
    const int E = in_sizes[1] / 2;
    const int ET = E + N;

    // workspace layout (all 256B aligned)
    char* w = (char*)d_ws;
    auto align = [](size_t x) { return (x + 255) & ~(size_t)255; };
    size_t o = 0;
    float* xl = (float*)(w + o);  o += align((size_t)N * HCC * 4);
    float* a_s = (float*)(w + o); o += align((size_t)N * HEADS * 4);
    float* a_d = (float*)(w + o); o += align((size_t)N * HEADS * 4);
    int* deg = (int*)(w + o);     o += align((size_t)N * 4);
    int* rowptr = (int*)(w + o);  o += align((size_t)(N + 1) * 4);
    int* fill = (int*)(w + o);    o += align((size_t)N * 4);
    int* eid = (int*)(w + o);     o += align((size_t)ET * 4);
    int* part = (int*)(w + o);    o += align((size_t)N * 4);
    int* bsum = (int*)(w + o);    o += align(512 * 4);
    int* binc = (int*)(w + o);    o += align(512 * 4);

    // 1. linear projection
    dim3 g1((N + 63) / 64, HCC / 64);
    k_gemm<<<g1, 256, 0, stream>>>(X, W, xl, N);

    // 2. attention logits
    k_att<<<(N + 3) / 4, 256, 0, stream>>>(xl, ASRC, ADST, a_s, a_d, N);

    // 3. CSR build (dst-sorted incoming edge lists, incl. self loops)
    hipMemsetAsync(deg, 0, (size_t)N * 4, stream);
    k_deg<<<(ET + 255) / 256, 256, 0, stream>>>(EI, deg, E, N);
    int nb1 = (N + 255) / 256;
    k_scan1<<<nb1, 256, 0, stream>>>(deg, part, bsum, N);
    k_scan2<<<1, 512, 0, stream>>>(bsum, binc, nb1);
    k_scan3<<<nb1, 256, 0, stream>>>(part, binc, rowptr, N);
    hipMemcpyAsync(fill, rowptr, (size_t)N * 4, hipMemcpyDeviceToDevice,
                   stream);
    k_scatter<<<(ET + 255) / 256, 256, 0, stream>>>(EI, fill, eid, E, N);

    // 4. per-dst softmax + weighted aggregation
    k_agg<<<N, 256, 0, stream>>>(rowptr, eid, a_s, a_d, xl, BIAS, OUT);
}

// Round 2
// 545.063 us; speedup vs baseline: 1.4560x; 1.4560x over previous
//
#include <hip/hip_runtime.h>

#define IN_CH  256
#define HCC    256   // HEADS*OUT_CH
#define HEADS  4
#define OUTC   64
#define NEG_SLOPE 0.2f

__device__ __forceinline__ unsigned short f2bf(float f) {
    unsigned u = __float_as_uint(f);
    unsigned r = (u + 0x7fffu + ((u >> 16) & 1u)) >> 16;  // RNE
    return (unsigned short)r;
}
__device__ __forceinline__ float bf2f(unsigned short b) {
    return __uint_as_float((unsigned)b << 16);
}

// ---------------------------------------------------------------------------
// Kernel 1: x_lin = X @ W   (fp32 compute, 64x64 tile) -> bf16 output
// ---------------------------------------------------------------------------
__global__ __launch_bounds__(256) void k_gemm(const float* __restrict__ X,
                                              const float* __restrict__ W,
                                              unsigned short* __restrict__ XLB,
                                              int N) {
    __shared__ float Ats[64][68];  // [k][m]
    __shared__ float Bs[64][68];   // [k][n]
    const int tid = threadIdx.x;
    const int tx = tid & 15, ty = tid >> 4;
    const int m0 = blockIdx.x * 64;
    const int n0 = blockIdx.y * 64;
    float acc[4][4] = {{0.f, 0.f, 0.f, 0.f}};

    for (int kb = 0; kb < IN_CH; kb += 64) {
#pragma unroll
        for (int it = 0; it < 4; ++it) {
            int v = tid + 256 * it;
            int row = v >> 4;          // 0..63
            int c4 = (v & 15) << 2;    // 0..60
            int gr = m0 + row;
            float4 av = make_float4(0.f, 0.f, 0.f, 0.f);
            if (gr < N) av = *(const float4*)(X + (size_t)gr * IN_CH + kb + c4);
            Ats[c4 + 0][row] = av.x;
            Ats[c4 + 1][row] = av.y;
            Ats[c4 + 2][row] = av.z;
            Ats[c4 + 3][row] = av.w;
            float4 bv = *(const float4*)(W + (size_t)(kb + row) * HCC + n0 + c4);
            *(float4*)&Bs[row][c4] = bv;
        }
        __syncthreads();
#pragma unroll 8
        for (int k = 0; k < 64; ++k) {
            float4 a = *(const float4*)&Ats[k][ty << 2];
            float4 b = *(const float4*)&Bs[k][tx << 2];
            float av4[4] = {a.x, a.y, a.z, a.w};
            float bv4[4] = {b.x, b.y, b.z, b.w};
#pragma unroll
            for (int i = 0; i < 4; ++i)
#pragma unroll
                for (int j = 0; j < 4; ++j)
                    acc[i][j] = fmaf(av4[i], bv4[j], acc[i][j]);
        }
        __syncthreads();
    }
#pragma unroll
    for (int i = 0; i < 4; ++i) {
        int gr = m0 + (ty << 2) + i;
        if (gr < N) {
            ushort4 ob;
            ob.x = f2bf(acc[i][0]);
            ob.y = f2bf(acc[i][1]);
            ob.z = f2bf(acc[i][2]);
            ob.w = f2bf(acc[i][3]);
            *(ushort4*)(XLB + (size_t)gr * HCC + n0 + (tx << 2)) = ob;
        }
    }
}

// ---------------------------------------------------------------------------
// Kernel 2: per-node attention logits from bf16 x_lin.
// One wave per node; lane l covers channels 4l..4l+3 (head = l>>4);
// 16-lane shuffle reduce per head.
// ---------------------------------------------------------------------------
__global__ __launch_bounds__(256) void k_att(const unsigned short* __restrict__ XLB,
                                             const float* __restrict__ ASRC,
                                             const float* __restrict__ ADST,
                                             float* __restrict__ a_s,
                                             float* __restrict__ a_d, int N) {
    int wid = threadIdx.x >> 6;
    int lane = threadIdx.x & 63;
    int n = blockIdx.x * 4 + wid;
    if (n >= N) return;
    ushort4 xv = *(const ushort4*)(XLB + (size_t)n * HCC + lane * 4);
    float x0 = bf2f(xv.x), x1 = bf2f(xv.y), x2 = bf2f(xv.z), x3 = bf2f(xv.w);
    int h = lane >> 4;
    int c4 = (lane & 15) << 2;
    float4 sv = *(const float4*)(ASRC + h * OUTC + c4);
    float4 dv = *(const float4*)(ADST + h * OUTC + c4);
    float ds = x0 * sv.x + x1 * sv.y + x2 * sv.z + x3 * sv.w;
    float dd = x0 * dv.x + x1 * dv.y + x2 * dv.z + x3 * dv.w;
#pragma unroll
    for (int o = 1; o < 16; o <<= 1) {
        ds += __shfl_xor(ds, o);
        dd += __shfl_xor(dd, o);
    }
    if ((lane & 15) == 0) {
        a_s[(size_t)n * HEADS + h] = ds;
        a_d[(size_t)n * HEADS + h] = dd;
    }
}

// ---------------------------------------------------------------------------
// CSR build: degree histogram, 2-level scan, scatter.
// Self-loops appended as indices E..E+N-1.
// ---------------------------------------------------------------------------
__global__ void k_deg(const int* __restrict__ ei, int* __restrict__ deg,
                      int E, int N) {
    int i = blockIdx.x * 256 + threadIdx.x;
    int ET = E + N;
    if (i >= ET) return;
    int dst = (i < E) ? ei[E + i] : (i - E);
    atomicAdd(&deg[dst], 1);
}

__global__ void k_scan1(const int* __restrict__ in, int* __restrict__ part,
                        int* __restrict__ bsum, int N) {
    __shared__ int s[256];
    int t = threadIdx.x;
    int i = blockIdx.x * 256 + t;
    int v = (i < N) ? in[i] : 0;
    s[t] = v;
    __syncthreads();
    for (int off = 1; off < 256; off <<= 1) {
        int x = (t >= off) ? s[t - off] : 0;
        __syncthreads();
        s[t] += x;
        __syncthreads();
    }
    if (i < N) part[i] = s[t];
    if (t == 255) bsum[blockIdx.x] = s[255];
}

__global__ void k_scan2(const int* __restrict__ bsum, int* __restrict__ binc,
                        int nb) {
    __shared__ int s[512];
    int t = threadIdx.x;
    s[t] = (t < nb) ? bsum[t] : 0;
    __syncthreads();
    for (int off = 1; off < 512; off <<= 1) {
        int x = (t >= off) ? s[t - off] : 0;
        __syncthreads();
        s[t] += x;
        __syncthreads();
    }
    binc[t] = s[t];
}

__global__ void k_scan3(const int* __restrict__ part,
                        const int* __restrict__ binc,
                        int* __restrict__ rowptr, int N) {
    int b = blockIdx.x;
    int i = b * 256 + threadIdx.x;
    if (i >= N) return;
    int off = (b > 0) ? binc[b - 1] : 0;
    rowptr[i + 1] = part[i] + off;
    if (i == 0) rowptr[0] = 0;
}

__global__ void k_scatter(const int* __restrict__ ei, int* __restrict__ fill,
                          int* __restrict__ eid, int E, int N) {
    int i = blockIdx.x * 256 + threadIdx.x;
    int ET = E + N;
    if (i >= ET) return;
    int src, dst;
    if (i < E) {
        src = ei[i];
        dst = ei[E + i];
    } else {
        src = dst = i - E;
    }
    int pos = atomicAdd(&fill[dst], 1);
    eid[pos] = src;
}

// ---------------------------------------------------------------------------
// Kernel 3: per-dst softmax + aggregation. One WAVE per node.
// Lane l owns channels 4l..4l+3 (head h = l>>4, uniform per 16-lane group).
// No max subtraction: logits are O(8), exp() safe in fp32; softmax ratio is
// mathematically identical. bf16 gather (512B/row), fp32 accumulate.
// ---------------------------------------------------------------------------
__global__ __launch_bounds__(256) void k_agg(const int* __restrict__ rowptr,
                                             const int* __restrict__ eid,
                                             const float* __restrict__ a_s,
                                             const float* __restrict__ a_d,
                                             const unsigned short* __restrict__ XLB,
                                             const float* __restrict__ BIAS,
                                             float* __restrict__ OUT, int N) {
    int wid = threadIdx.x >> 6;
    int lane = threadIdx.x & 63;
    int n = blockIdx.x * 4 + wid;
    if (n >= N) return;
    int h = lane >> 4;
    int s0 = rowptr[n];
    int s1 = rowptr[n + 1];
    float adn = a_d[(size_t)n * HEADS + h];
    float s = 0.f;
    float acc0 = 0.f, acc1 = 0.f, acc2 = 0.f, acc3 = 0.f;
    int src = (s0 < s1) ? eid[s0] : 0;
    for (int e = s0; e < s1; ++e) {
        int nsrc = (e + 1 < s1) ? eid[e + 1] : src;  // prefetch next index
        float l = a_s[(size_t)src * HEADS + h] + adn;
        l = fmaxf(l, NEG_SLOPE * l);                 // leaky relu
        float p = __expf(l);
        ushort4 xv = *(const ushort4*)(XLB + (size_t)src * HCC + lane * 4);
        s += p;
        acc0 = fmaf(p, bf2f(xv.x), acc0);
        acc1 = fmaf(p, bf2f(xv.y), acc1);
        acc2 = fmaf(p, bf2f(xv.z), acc2);
        acc3 = fmaf(p, bf2f(xv.w), acc3);
        src = nsrc;
    }
    float inv = 1.f / (s + 1e-16f);
    float4 b = *(const float4*)(BIAS + lane * 4);
    float4 o;
    o.x = acc0 * inv + b.x;
    o.y = acc1 * inv + b.y;
    o.z = acc2 * inv + b.z;
    o.w = acc3 * inv + b.w;
    *(float4*)(OUT + (size_t)n * HCC + lane * 4) = o;
}

// ---------------------------------------------------------------------------
extern "C" void kernel_launch(void* const* d_in, const int* in_sizes, int n_in,
                              void* d_out, int out_size, void* d_ws,
                              size_t ws_size, hipStream_t stream) {
    const float* X = (const float*)d_in[0];
    const int* EI = (const int*)d_in[1];
    const float* W = (const float*)d_in[2];
    const float* ASRC = (const float*)d_in[3];
    const float* ADST = (const float*)d_in[4];
    const float* BIAS = (const float*)d_in[5];
    float* OUT = (float*)d_out;

    const int N = in_sizes[0] / IN_CH;
    const int E = in_sizes[1] / 2;
    const int ET = E + N;

    // workspace layout (all 256B aligned)
    char* w = (char*)d_ws;
    auto align = [](size_t x) { return (x + 255) & ~(size_t)255; };
    size_t o = 0;
    unsigned short* xlb = (unsigned short*)(w + o); o += align((size_t)N * HCC * 2);
    float* a_s = (float*)(w + o); o += align((size_t)N * HEADS * 4);
    float* a_d = (float*)(w + o); o += align((size_t)N * HEADS * 4);
    int* deg = (int*)(w + o);     o += align((size_t)N * 4);
    int* rowptr = (int*)(w + o);  o += align((size_t)(N + 1) * 4);
    int* fill = (int*)(w + o);    o += align((size_t)N * 4);
    int* eid = (int*)(w + o);     o += align((size_t)ET * 4);
    int* part = (int*)(w + o);    o += align((size_t)N * 4);
    int* bsum = (int*)(w + o);    o += align(512 * 4);
    int* binc = (int*)(w + o);    o += align(512 * 4);

    // 1. linear projection -> bf16 x_lin
    dim3 g1((N + 63) / 64, HCC / 64);
    k_gemm<<<g1, 256, 0, stream>>>(X, W, xlb, N);

    // 2. attention logits
    k_att<<<(N + 3) / 4, 256, 0, stream>>>(xlb, ASRC, ADST, a_s, a_d, N);

    // 3. CSR build (dst-sorted incoming edge lists, incl. self loops)
    hipMemsetAsync(deg, 0, (size_t)N * 4, stream);
    k_deg<<<(ET + 255) / 256, 256, 0, stream>>>(EI, deg, E, N);
    int nb1 = (N + 255) / 256;
    k_scan1<<<nb1, 256, 0, stream>>>(deg, part, bsum, N);
    k_scan2<<<1, 512, 0, stream>>>(bsum, binc, nb1);
    k_scan3<<<nb1, 256, 0, stream>>>(part, binc, rowptr, N);
    hipMemcpyAsync(fill, rowptr, (size_t)N * 4, hipMemcpyDeviceToDevice,
                   stream);
    k_scatter<<<(ET + 255) / 256, 256, 0, stream>>>(EI, fill, eid, E, N);

    // 4. per-dst softmax + weighted aggregation (one wave per node)
    k_agg<<<(N + 3) / 4, 256, 0, stream>>>(rowptr, eid, a_s, a_d, xlb, BIAS,
                                           OUT, N);
}

// Round 3
// 429.518 us; speedup vs baseline: 1.8477x; 1.2690x over previous
//
#include <hip/hip_runtime.h>

#define IN_CH  256
#define HCC    256   // HEADS*OUT_CH
#define HEADS  4
#define OUTC   64
#define NEG_SLOPE 0.2f

using short8v = __attribute__((ext_vector_type(8))) short;
using f32x4   = __attribute__((ext_vector_type(4))) float;

__device__ __forceinline__ unsigned short f2bf(float f) {
    unsigned u = __float_as_uint(f);
    unsigned r = (u + 0x7fffu + ((u >> 16) & 1u)) >> 16;  // RNE
    return (unsigned short)r;
}
__device__ __forceinline__ float bf2f(unsigned short b) {
    return __uint_as_float((unsigned)b << 16);
}

// ---------------------------------------------------------------------------
// Kernel 0: W [K=256][N=256] fp32 -> WT [N][K] bf16 (tiny, one-time)
// ---------------------------------------------------------------------------
__global__ void k_wt(const float* __restrict__ W,
                     unsigned short* __restrict__ WT) {
    int n = blockIdx.x;
    int k = threadIdx.x;
    WT[n * IN_CH + k] = f2bf(W[(size_t)k * HCC + n]);
}

// ---------------------------------------------------------------------------
// Kernel 1: x_lin = X @ W via bf16 MFMA. BM=64, BN=256 (full width -> X read
// once), BK=64. 4 waves, wave w owns cols w*64..w*64+63 (4x4 16x16 frags).
// A converted fp32->bf16 during reg staging; B from WT (bf16, K-contiguous).
// LDS rows padded to 72 elems (144B) -> frag reads are 2-way aliases (free).
// ---------------------------------------------------------------------------
__global__ __launch_bounds__(256) void k_gemm(const float* __restrict__ X,
                                              const unsigned short* __restrict__ WT,
                                              unsigned short* __restrict__ XLB,
                                              int N) {
    __shared__ unsigned short Ats[64][72];   // [m][k]
    __shared__ unsigned short Bs[256][72];   // [n][k]
    const int tid = threadIdx.x;
    const int lane = tid & 63;
    const int wid = tid >> 6;
    const int m0 = blockIdx.x * 64;
    const int r16 = lane & 15;
    const int g = lane >> 4;

    f32x4 acc[4][4];
    const f32x4 z = {0.f, 0.f, 0.f, 0.f};
#pragma unroll
    for (int m = 0; m < 4; ++m)
#pragma unroll
        for (int n = 0; n < 4; ++n) acc[m][n] = z;

    for (int kb = 0; kb < IN_CH; kb += 64) {
        // stage A: 64 rows x 64 k, fp32 -> bf16
#pragma unroll
        for (int it = 0; it < 4; ++it) {
            int v = tid + 256 * it;
            int row = v >> 4;          // 0..63
            int c4 = (v & 15) << 2;    // 0..60
            int gr = m0 + row;
            float4 av = make_float4(0.f, 0.f, 0.f, 0.f);
            if (gr < N) av = *(const float4*)(X + (size_t)gr * IN_CH + kb + c4);
            ushort4 ab;
            ab.x = f2bf(av.x); ab.y = f2bf(av.y);
            ab.z = f2bf(av.z); ab.w = f2bf(av.w);
            *(ushort4*)&Ats[row][c4] = ab;
        }
        // stage B: 256 n x 64 k bf16 from WT
#pragma unroll
        for (int it = 0; it < 8; ++it) {
            int v = tid + 256 * it;
            int brow = v >> 3;         // 0..255
            int c8 = (v & 7) << 3;     // 0..56
            short8v bv = *(const short8v*)(WT + (size_t)brow * IN_CH + kb + c8);
            *(short8v*)&Bs[brow][c8] = bv;
        }
        __syncthreads();
#pragma unroll
        for (int ks = 0; ks < 2; ++ks) {
            short8v af[4], bf[4];
#pragma unroll
            for (int m = 0; m < 4; ++m)
                af[m] = *(const short8v*)&Ats[m * 16 + r16][ks * 32 + g * 8];
#pragma unroll
            for (int n = 0; n < 4; ++n)
                bf[n] = *(const short8v*)&Bs[wid * 64 + n * 16 + r16][ks * 32 + g * 8];
#pragma unroll
            for (int m = 0; m < 4; ++m)
#pragma unroll
                for (int n = 0; n < 4; ++n)
                    acc[m][n] = __builtin_amdgcn_mfma_f32_16x16x32_bf16(
                        af[m], bf[n], acc[m][n], 0, 0, 0);
        }
        __syncthreads();
    }

    // epilogue: D frag layout col=lane&15, row=(lane>>4)*4+j  [m89-verified]
#pragma unroll
    for (int m = 0; m < 4; ++m) {
#pragma unroll
        for (int j = 0; j < 4; ++j) {
            int row = m0 + m * 16 + g * 4 + j;
            if (row < N) {
#pragma unroll
                for (int n = 0; n < 4; ++n) {
                    int col = wid * 64 + n * 16 + r16;
                    XLB[(size_t)row * HCC + col] = f2bf(acc[m][n][j]);
                }
            }
        }
    }
}

// ---------------------------------------------------------------------------
// Kernel 2: per-node attention logits from bf16 x_lin.
// ---------------------------------------------------------------------------
__global__ __launch_bounds__(256) void k_att(const unsigned short* __restrict__ XLB,
                                             const float* __restrict__ ASRC,
                                             const float* __restrict__ ADST,
                                             float* __restrict__ a_s,
                                             float* __restrict__ a_d, int N) {
    int wid = threadIdx.x >> 6;
    int lane = threadIdx.x & 63;
    int n = blockIdx.x * 4 + wid;
    if (n >= N) return;
    ushort4 xv = *(const ushort4*)(XLB + (size_t)n * HCC + lane * 4);
    float x0 = bf2f(xv.x), x1 = bf2f(xv.y), x2 = bf2f(xv.z), x3 = bf2f(xv.w);
    int h = lane >> 4;
    int c4 = (lane & 15) << 2;
    float4 sv = *(const float4*)(ASRC + h * OUTC + c4);
    float4 dv = *(const float4*)(ADST + h * OUTC + c4);
    float ds = x0 * sv.x + x1 * sv.y + x2 * sv.z + x3 * sv.w;
    float dd = x0 * dv.x + x1 * dv.y + x2 * dv.z + x3 * dv.w;
#pragma unroll
    for (int o = 1; o < 16; o <<= 1) {
        ds += __shfl_xor(ds, o);
        dd += __shfl_xor(dd, o);
    }
    if ((lane & 15) == 0) {
        a_s[(size_t)n * HEADS + h] = ds;
        a_d[(size_t)n * HEADS + h] = dd;
    }
}

// ---------------------------------------------------------------------------
// CSR build: degree histogram, 2-level scan, scatter.
// ---------------------------------------------------------------------------
__global__ void k_deg(const int* __restrict__ ei, int* __restrict__ deg,
                      int E, int N) {
    int i = blockIdx.x * 256 + threadIdx.x;
    int ET = E + N;
    if (i >= ET) return;
    int dst = (i < E) ? ei[E + i] : (i - E);
    atomicAdd(&deg[dst], 1);
}

__global__ void k_scan1(const int* __restrict__ in, int* __restrict__ part,
                        int* __restrict__ bsum, int N) {
    __shared__ int s[256];
    int t = threadIdx.x;
    int i = blockIdx.x * 256 + t;
    int v = (i < N) ? in[i] : 0;
    s[t] = v;
    __syncthreads();
    for (int off = 1; off < 256; off <<= 1) {
        int x = (t >= off) ? s[t - off] : 0;
        __syncthreads();
        s[t] += x;
        __syncthreads();
    }
    if (i < N) part[i] = s[t];
    if (t == 255) bsum[blockIdx.x] = s[255];
}

__global__ void k_scan2(const int* __restrict__ bsum, int* __restrict__ binc,
                        int nb) {
    __shared__ int s[512];
    int t = threadIdx.x;
    s[t] = (t < nb) ? bsum[t] : 0;
    __syncthreads();
    for (int off = 1; off < 512; off <<= 1) {
        int x = (t >= off) ? s[t - off] : 0;
        __syncthreads();
        s[t] += x;
        __syncthreads();
    }
    binc[t] = s[t];
}

__global__ void k_scan3(const int* __restrict__ part,
                        const int* __restrict__ binc,
                        int* __restrict__ rowptr, int N) {
    int b = blockIdx.x;
    int i = b * 256 + threadIdx.x;
    if (i >= N) return;
    int off = (b > 0) ? binc[b - 1] : 0;
    rowptr[i + 1] = part[i] + off;
    if (i == 0) rowptr[0] = 0;
}

__global__ void k_scatter(const int* __restrict__ ei, int* __restrict__ fill,
                          int* __restrict__ eid, int E, int N) {
    int i = blockIdx.x * 256 + threadIdx.x;
    int ET = E + N;
    if (i >= ET) return;
    int src, dst;
    if (i < E) {
        src = ei[i];
        dst = ei[E + i];
    } else {
        src = dst = i - E;
    }
    int pos = atomicAdd(&fill[dst], 1);
    eid[pos] = src;
}

// ---------------------------------------------------------------------------
// Kernel 3: per-dst softmax + aggregation. One WAVE per node.
// Lane l owns channels 4l..4l+3 (head h = l>>4). No max subtraction (logits
// O(8), exp safe in fp32). bf16 gather, fp32 accumulate.
// ---------------------------------------------------------------------------
__global__ __launch_bounds__(256) void k_agg(const int* __restrict__ rowptr,
                                             const int* __restrict__ eid,
                                             const float* __restrict__ a_s,
                                             const float* __restrict__ a_d,
                                             const unsigned short* __restrict__ XLB,
                                             const float* __restrict__ BIAS,
                                             float* __restrict__ OUT, int N) {
    int wid = threadIdx.x >> 6;
    int lane = threadIdx.x & 63;
    int n = blockIdx.x * 4 + wid;
    if (n >= N) return;
    int h = lane >> 4;
    int s0 = rowptr[n];
    int s1 = rowptr[n + 1];
    float adn = a_d[(size_t)n * HEADS + h];
    float s = 0.f;
    float acc0 = 0.f, acc1 = 0.f, acc2 = 0.f, acc3 = 0.f;
    int src = (s0 < s1) ? eid[s0] : 0;
    for (int e = s0; e < s1; ++e) {
        int nsrc = (e + 1 < s1) ? eid[e + 1] : src;  // prefetch next index
        float l = a_s[(size_t)src * HEADS + h] + adn;
        l = fmaxf(l, NEG_SLOPE * l);                 // leaky relu
        float p = __expf(l);
        ushort4 xv = *(const ushort4*)(XLB + (size_t)src * HCC + lane * 4);
        s += p;
        acc0 = fmaf(p, bf2f(xv.x), acc0);
        acc1 = fmaf(p, bf2f(xv.y), acc1);
        acc2 = fmaf(p, bf2f(xv.z), acc2);
        acc3 = fmaf(p, bf2f(xv.w), acc3);
        src = nsrc;
    }
    float inv = 1.f / (s + 1e-16f);
    float4 b = *(const float4*)(BIAS + lane * 4);
    float4 o;
    o.x = acc0 * inv + b.x;
    o.y = acc1 * inv + b.y;
    o.z = acc2 * inv + b.z;
    o.w = acc3 * inv + b.w;
    *(float4*)(OUT + (size_t)n * HCC + lane * 4) = o;
}

// ---------------------------------------------------------------------------
extern "C" void kernel_launch(void* const* d_in, const int* in_sizes, int n_in,
                              void* d_out, int out_size, void* d_ws,
                              size_t ws_size, hipStream_t stream) {
    const float* X = (const float*)d_in[0];
    const int* EI = (const int*)d_in[1];
    const float* W = (const float*)d_in[2];
    const float* ASRC = (const float*)d_in[3];
    const float* ADST = (const float*)d_in[4];
    const float* BIAS = (const float*)d_in[5];
    float* OUT = (float*)d_out;

    const int N = in_sizes[0] / IN_CH;
    const int E = in_sizes[1] / 2;
    const int ET = E + N;

    // workspace layout (all 256B aligned)
    char* w = (char*)d_ws;
    auto align = [](size_t x) { return (x + 255) & ~(size_t)255; };
    size_t o = 0;
    unsigned short* xlb = (unsigned short*)(w + o); o += align((size_t)N * HCC * 2);
    unsigned short* wt = (unsigned short*)(w + o);  o += align((size_t)IN_CH * HCC * 2);
    float* a_s = (float*)(w + o); o += align((size_t)N * HEADS * 4);
    float* a_d = (float*)(w + o); o += align((size_t)N * HEADS * 4);
    int* deg = (int*)(w + o);     o += align((size_t)N * 4);
    int* rowptr = (int*)(w + o);  o += align((size_t)(N + 1) * 4);
    int* fill = (int*)(w + o);    o += align((size_t)N * 4);
    int* eid = (int*)(w + o);     o += align((size_t)ET * 4);
    int* part = (int*)(w + o);    o += align((size_t)N * 4);
    int* bsum = (int*)(w + o);    o += align(512 * 4);
    int* binc = (int*)(w + o);    o += align(512 * 4);

    // 0. W -> WT (bf16, transposed)
    k_wt<<<HCC, IN_CH, 0, stream>>>(W, wt);

    // 1. linear projection -> bf16 x_lin (MFMA)
    k_gemm<<<(N + 63) / 64, 256, 0, stream>>>(X, wt, xlb, N);

    // 2. attention logits
    k_att<<<(N + 3) / 4, 256, 0, stream>>>(xlb, ASRC, ADST, a_s, a_d, N);

    // 3. CSR build (dst-sorted incoming edge lists, incl. self loops)
    hipMemsetAsync(deg, 0, (size_t)N * 4, stream);
    k_deg<<<(ET + 255) / 256, 256, 0, stream>>>(EI, deg, E, N);
    int nb1 = (N + 255) / 256;
    k_scan1<<<nb1, 256, 0, stream>>>(deg, part, bsum, N);
    k_scan2<<<1, 512, 0, stream>>>(bsum, binc, nb1);
    k_scan3<<<nb1, 256, 0, stream>>>(part, binc, rowptr, N);
    hipMemcpyAsync(fill, rowptr, (size_t)N * 4, hipMemcpyDeviceToDevice,
                   stream);
    k_scatter<<<(ET + 255) / 256, 256, 0, stream>>>(EI, fill, eid, E, N);

    // 4. per-dst softmax + weighted aggregation (one wave per node)
    k_agg<<<(N + 3) / 4, 256, 0, stream>>>(rowptr, eid, a_s, a_d, xlb, BIAS,
                                           OUT, N);
}

// Round 4
// 399.563 us; speedup vs baseline: 1.9862x; 1.0750x over previous
//
#include <hip/hip_runtime.h>

#define IN_CH  256
#define HCC    256   // HEADS*OUT_CH
#define HEADS  4
#define OUTC   64
#define NEG_SLOPE 0.2f

using short8v = __attribute__((ext_vector_type(8))) short;
using f32x4   = __attribute__((ext_vector_type(4))) float;

__device__ __forceinline__ unsigned short f2bf(float f) {
    unsigned u = __float_as_uint(f);
    unsigned r = (u + 0x7fffu + ((u >> 16) & 1u)) >> 16;  // RNE
    return (unsigned short)r;
}
__device__ __forceinline__ float bf2f(unsigned short b) {
    return __uint_as_float((unsigned)b << 16);
}

// ---------------------------------------------------------------------------
// Kernel 0: W [K=256][N=256] fp32 -> WT [N][K] bf16 (tiny, one-time)
// ---------------------------------------------------------------------------
__global__ void k_wt(const float* __restrict__ W,
                     unsigned short* __restrict__ WT) {
    int n = blockIdx.x;
    int k = threadIdx.x;
    WT[n * IN_CH + k] = f2bf(W[(size_t)k * HCC + n]);
}

// ---------------------------------------------------------------------------
// Kernel 1: x_lin = X @ W via bf16 MFMA, BM=64, BN=256 (X read once), BK=64.
// Wave w owns cols w*64..w*64+63 == head w's channels, so the attention
// logit dots (a_src, a_dst) are fused into the epilogue from fp32 acc:
// 4 FMA + 16-lane shfl_xor reduce per output row. k_att is gone.
// ---------------------------------------------------------------------------
__global__ __launch_bounds__(256) void k_gemm(const float* __restrict__ X,
                                              const unsigned short* __restrict__ WT,
                                              const float* __restrict__ ASRC,
                                              const float* __restrict__ ADST,
                                              unsigned short* __restrict__ XLB,
                                              float* __restrict__ a_s,
                                              float* __restrict__ a_d,
                                              int N) {
    __shared__ unsigned short Ats[64][72];   // [m][k]
    __shared__ unsigned short Bs[256][72];   // [n][k]
    const int tid = threadIdx.x;
    const int lane = tid & 63;
    const int wid = tid >> 6;
    const int m0 = blockIdx.x * 64;
    const int r16 = lane & 15;
    const int g = lane >> 4;

    f32x4 acc[4][4];
    const f32x4 z = {0.f, 0.f, 0.f, 0.f};
#pragma unroll
    for (int m = 0; m < 4; ++m)
#pragma unroll
        for (int n = 0; n < 4; ++n) acc[m][n] = z;

    for (int kb = 0; kb < IN_CH; kb += 64) {
        // stage A: 64 rows x 64 k, fp32 -> bf16
#pragma unroll
        for (int it = 0; it < 4; ++it) {
            int v = tid + 256 * it;
            int row = v >> 4;          // 0..63
            int c4 = (v & 15) << 2;    // 0..60
            int gr = m0 + row;
            float4 av = make_float4(0.f, 0.f, 0.f, 0.f);
            if (gr < N) av = *(const float4*)(X + (size_t)gr * IN_CH + kb + c4);
            ushort4 ab;
            ab.x = f2bf(av.x); ab.y = f2bf(av.y);
            ab.z = f2bf(av.z); ab.w = f2bf(av.w);
            *(ushort4*)&Ats[row][c4] = ab;
        }
        // stage B: 256 n x 64 k bf16 from WT
#pragma unroll
        for (int it = 0; it < 8; ++it) {
            int v = tid + 256 * it;
            int brow = v >> 3;         // 0..255
            int c8 = (v & 7) << 3;     // 0..56
            short8v bv = *(const short8v*)(WT + (size_t)brow * IN_CH + kb + c8);
            *(short8v*)&Bs[brow][c8] = bv;
        }
        __syncthreads();
#pragma unroll
        for (int ks = 0; ks < 2; ++ks) {
            short8v af[4], bf[4];
#pragma unroll
            for (int m = 0; m < 4; ++m)
                af[m] = *(const short8v*)&Ats[m * 16 + r16][ks * 32 + g * 8];
#pragma unroll
            for (int n = 0; n < 4; ++n)
                bf[n] = *(const short8v*)&Bs[wid * 64 + n * 16 + r16][ks * 32 + g * 8];
#pragma unroll
            for (int m = 0; m < 4; ++m)
#pragma unroll
                for (int n = 0; n < 4; ++n)
                    acc[m][n] = __builtin_amdgcn_mfma_f32_16x16x32_bf16(
                        af[m], bf[n], acc[m][n], 0, 0, 0);
        }
        __syncthreads();
    }

    // att coefficients for this wave's head (h = wid), cols n*16+r16
    const int h = wid;
    float asc[4], adc[4];
#pragma unroll
    for (int n = 0; n < 4; ++n) {
        asc[n] = ASRC[h * OUTC + n * 16 + r16];
        adc[n] = ADST[h * OUTC + n * 16 + r16];
    }

    // epilogue: D frag layout col=lane&15, row=(lane>>4)*4+j  [m89-verified]
#pragma unroll
    for (int m = 0; m < 4; ++m) {
#pragma unroll
        for (int j = 0; j < 4; ++j) {
            int row = m0 + m * 16 + g * 4 + j;
            float ds = 0.f, dd = 0.f;
#pragma unroll
            for (int n = 0; n < 4; ++n) {
                ds = fmaf(acc[m][n][j], asc[n], ds);
                dd = fmaf(acc[m][n][j], adc[n], dd);
            }
#pragma unroll
            for (int o = 1; o < 16; o <<= 1) {
                ds += __shfl_xor(ds, o);
                dd += __shfl_xor(dd, o);
            }
            if (row < N) {
                if (r16 == 0) {
                    a_s[(size_t)row * HEADS + h] = ds;
                    a_d[(size_t)row * HEADS + h] = dd;
                }
#pragma unroll
                for (int n = 0; n < 4; ++n) {
                    int col = wid * 64 + n * 16 + r16;
                    XLB[(size_t)row * HCC + col] = f2bf(acc[m][n][j]);
                }
            }
        }
    }
}

// ---------------------------------------------------------------------------
// CSR build: degree histogram, 2-level scan, scatter.
// ---------------------------------------------------------------------------
__global__ void k_deg(const int* __restrict__ ei, int* __restrict__ deg,
                      int E, int N) {
    int i = blockIdx.x * 256 + threadIdx.x;
    int ET = E + N;
    if (i >= ET) return;
    int dst = (i < E) ? ei[E + i] : (i - E);
    atomicAdd(&deg[dst], 1);
}

__global__ void k_scan1(const int* __restrict__ in, int* __restrict__ part,
                        int* __restrict__ bsum, int N) {
    __shared__ int s[256];
    int t = threadIdx.x;
    int i = blockIdx.x * 256 + t;
    int v = (i < N) ? in[i] : 0;
    s[t] = v;
    __syncthreads();
    for (int off = 1; off < 256; off <<= 1) {
        int x = (t >= off) ? s[t - off] : 0;
        __syncthreads();
        s[t] += x;
        __syncthreads();
    }
    if (i < N) part[i] = s[t];
    if (t == 255) bsum[blockIdx.x] = s[255];
}

__global__ void k_scan2(const int* __restrict__ bsum, int* __restrict__ binc,
                        int nb) {
    __shared__ int s[512];
    int t = threadIdx.x;
    s[t] = (t < nb) ? bsum[t] : 0;
    __syncthreads();
    for (int off = 1; off < 512; off <<= 1) {
        int x = (t >= off) ? s[t - off] : 0;
        __syncthreads();
        s[t] += x;
        __syncthreads();
    }
    binc[t] = s[t];
}

__global__ void k_scan3(const int* __restrict__ part,
                        const int* __restrict__ binc,
                        int* __restrict__ rowptr, int N) {
    int b = blockIdx.x;
    int i = b * 256 + threadIdx.x;
    if (i >= N) return;
    int off = (b > 0) ? binc[b - 1] : 0;
    rowptr[i + 1] = part[i] + off;
    if (i == 0) rowptr[0] = 0;
}

__global__ void k_scatter(const int* __restrict__ ei, int* __restrict__ fill,
                          int* __restrict__ eid, int E, int N) {
    int i = blockIdx.x * 256 + threadIdx.x;
    int ET = E + N;
    if (i >= ET) return;
    int src, dst;
    if (i < E) {
        src = ei[i];
        dst = ei[E + i];
    } else {
        src = dst = i - E;
    }
    int pos = atomicAdd(&fill[dst], 1);
    eid[pos] = src;
}

// ---------------------------------------------------------------------------
// Kernel 3: per-dst softmax + aggregation. One WAVE per node, lane owns 4
// channels. Unrolled by 4 edges: 4 independent a_s loads + 4 independent
// row gathers in flight per iteration (latency hiding). No max subtraction
// (logits O(8), fp32 exp safe).
// ---------------------------------------------------------------------------
__global__ __launch_bounds__(256) void k_agg(const int* __restrict__ rowptr,
                                             const int* __restrict__ eid,
                                             const float* __restrict__ a_s,
                                             const float* __restrict__ a_d,
                                             const unsigned short* __restrict__ XLB,
                                             const float* __restrict__ BIAS,
                                             float* __restrict__ OUT, int N) {
    int wid = threadIdx.x >> 6;
    int lane = threadIdx.x & 63;
    int n = blockIdx.x * 4 + wid;
    if (n >= N) return;
    int h = lane >> 4;
    int s0 = rowptr[n];
    int s1 = rowptr[n + 1];
    float adn = a_d[(size_t)n * HEADS + h];
    float s = 0.f;
    float acc0 = 0.f, acc1 = 0.f, acc2 = 0.f, acc3 = 0.f;

    int e = s0;
    for (; e + 4 <= s1; e += 4) {
        int i0 = eid[e + 0], i1 = eid[e + 1], i2 = eid[e + 2], i3 = eid[e + 3];
        float l0 = a_s[(size_t)i0 * HEADS + h] + adn;
        float l1 = a_s[(size_t)i1 * HEADS + h] + adn;
        float l2 = a_s[(size_t)i2 * HEADS + h] + adn;
        float l3 = a_s[(size_t)i3 * HEADS + h] + adn;
        ushort4 x0 = *(const ushort4*)(XLB + (size_t)i0 * HCC + lane * 4);
        ushort4 x1 = *(const ushort4*)(XLB + (size_t)i1 * HCC + lane * 4);
        ushort4 x2 = *(const ushort4*)(XLB + (size_t)i2 * HCC + lane * 4);
        ushort4 x3 = *(const ushort4*)(XLB + (size_t)i3 * HCC + lane * 4);
        l0 = fmaxf(l0, NEG_SLOPE * l0);
        l1 = fmaxf(l1, NEG_SLOPE * l1);
        l2 = fmaxf(l2, NEG_SLOPE * l2);
        l3 = fmaxf(l3, NEG_SLOPE * l3);
        float p0 = __expf(l0), p1 = __expf(l1);
        float p2 = __expf(l2), p3 = __expf(l3);
        s += (p0 + p1) + (p2 + p3);
        acc0 = fmaf(p0, bf2f(x0.x), acc0);
        acc1 = fmaf(p0, bf2f(x0.y), acc1);
        acc2 = fmaf(p0, bf2f(x0.z), acc2);
        acc3 = fmaf(p0, bf2f(x0.w), acc3);
        acc0 = fmaf(p1, bf2f(x1.x), acc0);
        acc1 = fmaf(p1, bf2f(x1.y), acc1);
        acc2 = fmaf(p1, bf2f(x1.z), acc2);
        acc3 = fmaf(p1, bf2f(x1.w), acc3);
        acc0 = fmaf(p2, bf2f(x2.x), acc0);
        acc1 = fmaf(p2, bf2f(x2.y), acc1);
        acc2 = fmaf(p2, bf2f(x2.z), acc2);
        acc3 = fmaf(p2, bf2f(x2.w), acc3);
        acc0 = fmaf(p3, bf2f(x3.x), acc0);
        acc1 = fmaf(p3, bf2f(x3.y), acc1);
        acc2 = fmaf(p3, bf2f(x3.z), acc2);
        acc3 = fmaf(p3, bf2f(x3.w), acc3);
    }
    for (; e < s1; ++e) {
        int src = eid[e];
        float l = a_s[(size_t)src * HEADS + h] + adn;
        l = fmaxf(l, NEG_SLOPE * l);
        float p = __expf(l);
        ushort4 xv = *(const ushort4*)(XLB + (size_t)src * HCC + lane * 4);
        s += p;
        acc0 = fmaf(p, bf2f(xv.x), acc0);
        acc1 = fmaf(p, bf2f(xv.y), acc1);
        acc2 = fmaf(p, bf2f(xv.z), acc2);
        acc3 = fmaf(p, bf2f(xv.w), acc3);
    }

    float inv = 1.f / (s + 1e-16f);
    float4 b = *(const float4*)(BIAS + lane * 4);
    float4 o;
    o.x = acc0 * inv + b.x;
    o.y = acc1 * inv + b.y;
    o.z = acc2 * inv + b.z;
    o.w = acc3 * inv + b.w;
    *(float4*)(OUT + (size_t)n * HCC + lane * 4) = o;
}

// ---------------------------------------------------------------------------
extern "C" void kernel_launch(void* const* d_in, const int* in_sizes, int n_in,
                              void* d_out, int out_size, void* d_ws,
                              size_t ws_size, hipStream_t stream) {
    const float* X = (const float*)d_in[0];
    const int* EI = (const int*)d_in[1];
    const float* W = (const float*)d_in[2];
    const float* ASRC = (const float*)d_in[3];
    const float* ADST = (const float*)d_in[4];
    const float* BIAS = (const float*)d_in[5];
    float* OUT = (float*)d_out;

    const int N = in_sizes[0] / IN_CH;
    const int E = in_sizes[1] / 2;
    const int ET = E + N;

    // workspace layout (all 256B aligned)
    char* w = (char*)d_ws;
    auto align = [](size_t x) { return (x + 255) & ~(size_t)255; };
    size_t o = 0;
    unsigned short* xlb = (unsigned short*)(w + o); o += align((size_t)N * HCC * 2);
    unsigned short* wt = (unsigned short*)(w + o);  o += align((size_t)IN_CH * HCC * 2);
    float* a_s = (float*)(w + o); o += align((size_t)N * HEADS * 4);
    float* a_d = (float*)(w + o); o += align((size_t)N * HEADS * 4);
    int* deg = (int*)(w + o);     o += align((size_t)N * 4);
    int* rowptr = (int*)(w + o);  o += align((size_t)(N + 1) * 4);
    int* fill = (int*)(w + o);    o += align((size_t)N * 4);
    int* eid = (int*)(w + o);     o += align((size_t)ET * 4);
    int* part = (int*)(w + o);    o += align((size_t)N * 4);
    int* bsum = (int*)(w + o);    o += align(512 * 4);
    int* binc = (int*)(w + o);    o += align(512 * 4);

    // 0. W -> WT (bf16, transposed)
    k_wt<<<HCC, IN_CH, 0, stream>>>(W, wt);

    // 1. linear projection -> bf16 x_lin + fused attention logits (MFMA)
    k_gemm<<<(N + 63) / 64, 256, 0, stream>>>(X, wt, ASRC, ADST, xlb, a_s,
                                              a_d, N);

    // 2. CSR build (dst-sorted incoming edge lists, incl. self loops)
    hipMemsetAsync(deg, 0, (size_t)N * 4, stream);
    k_deg<<<(ET + 255) / 256, 256, 0, stream>>>(EI, deg, E, N);
    int nb1 = (N + 255) / 256;
    k_scan1<<<nb1, 256, 0, stream>>>(deg, part, bsum, N);
    k_scan2<<<1, 512, 0, stream>>>(bsum, binc, nb1);
    k_scan3<<<nb1, 256, 0, stream>>>(part, binc, rowptr, N);
    hipMemcpyAsync(fill, rowptr, (size_t)N * 4, hipMemcpyDeviceToDevice,
                   stream);
    k_scatter<<<(ET + 255) / 256, 256, 0, stream>>>(EI, fill, eid, E, N);

    // 3. per-dst softmax + weighted aggregation (one wave per node)
    k_agg<<<(N + 3) / 4, 256, 0, stream>>>(rowptr, eid, a_s, a_d, xlb, BIAS,
                                           OUT, N);
}